// Round 16
// baseline (238.361 us; speedup 1.0000x reference)
//
#include <hip/hip_runtime.h>
#include <cstdint>
#include <cstddef>

// ---------------------------------------------------------------------------
// MultiHeadCoAttention: B=4, NCH=2, T=1024, U=1024, H=8, D_K=128, dk_co=256.
// v10: R10 counters: gemm_qkv bound-4 treatment CONFIRMED (62->56us, 920 TF
// = m97 plateau; MfmaUtil 33->38.5). (1) propagate bound 4 to gemm_out;
// (2) attention QK wave re-split: wave = 32q x 16s (was 16q x 32s) -> each
// kf LDS read feeds 2 MFMAs; per-wave/step b128 reads 26->18 (attention is
// LDS-read-bound per port-bandwidth model); (3) gemm_qkv unchanged (noise
// control, ~56us expected). [R11-R15: infra failures; ledger audited clean;
// resubmitted unchanged.]
// ---------------------------------------------------------------------------

typedef __bf16 bf16_t;
typedef __attribute__((ext_vector_type(8))) __bf16 bf16x8;
typedef __attribute__((ext_vector_type(4))) __bf16 bf16x4;
typedef __attribute__((ext_vector_type(4))) float f32x4;

// async global->LDS, 16B per lane; LDS dest = wave-uniform base + lane*16
__device__ __forceinline__ void async_copy16(const bf16_t* g, bf16_t* l) {
  auto* gp = reinterpret_cast<const __attribute__((address_space(1))) void*>(
      reinterpret_cast<uintptr_t>(g));
  auto* lp = reinterpret_cast<__attribute__((address_space(3))) void*>(
      reinterpret_cast<uintptr_t>(l));
  __builtin_amdgcn_global_load_lds(gp, lp, 16, 0, 0);
}

// barrier with LDS-write visibility only (keeps staged global loads in flight)
__device__ __forceinline__ void bar_lds() {
  asm volatile("s_waitcnt lgkmcnt(0)" ::: "memory");
  __builtin_amdgcn_s_barrier();
  __builtin_amdgcn_sched_barrier(0);
}

// end-of-step barrier: drain staged loads + all LDS ops
__device__ __forceinline__ void bar_vm() {
  asm volatile("s_waitcnt vmcnt(0) lgkmcnt(0)" ::: "memory");
  __builtin_amdgcn_s_barrier();
  __builtin_amdgcn_sched_barrier(0);
}

__device__ __forceinline__ void cast8(const float* s, bf16_t* d) {
  const float4 a = ((const float4*)s)[0];
  const float4 b = ((const float4*)s)[1];
  bf16x8 o;
  o[0] = (bf16_t)a.x; o[1] = (bf16_t)a.y; o[2] = (bf16_t)a.z; o[3] = (bf16_t)a.w;
  o[4] = (bf16_t)b.x; o[5] = (bf16_t)b.y; o[6] = (bf16_t)b.z; o[7] = (bf16_t)b.w;
  *(bf16x8*)d = o;
}

// ---------------------------------------------------------------------------
__global__ void cast_all(const float* __restrict__ x,
                         const float* __restrict__ Wq,
                         const float* __restrict__ Wk,
                         const float* __restrict__ Wv,
                         const float* __restrict__ Wo, bf16_t* __restrict__ xb,
                         bf16_t* __restrict__ wqkv, bf16_t* __restrict__ wob) {
  const int i = blockIdx.x * blockDim.x + threadIdx.x;
  if (i < 1048576) {
    cast8(x + (size_t)i * 8, xb + (size_t)i * 8);
  } else {
    const int j = i - 1048576;
    if (j < 393216) {
      const int seg = j >> 17;  // 131072 groups per weight
      const float* w = (seg == 0) ? Wq : ((seg == 1) ? Wk : Wv);
      cast8(w + (size_t)(j - seg * 131072) * 8, wqkv + (size_t)j * 8);
    } else if (j < 524288) {
      cast8(Wo + (size_t)(j - 393216) * 8, wob + (size_t)(j - 393216) * 8);
    }
  }
}

// ---------------------------------------------------------------------------
// Fused QKV GEMM (v5/m97 structure): C[8192,3072] = xb @ Wqkv^T.
// launch_bounds(256,4): CONFIRMED R10 (62->56us). UNCHANGED (noise control).
__global__ __launch_bounds__(256, 4) void gemm_qkv(
    const bf16_t* __restrict__ A, const bf16_t* __restrict__ W,
    const float* __restrict__ bq, const float* __restrict__ bk,
    const float* __restrict__ bv, bf16_t* __restrict__ qb,
    bf16_t* __restrict__ kb, bf16_t* __restrict__ vtb, float qscale) {
  __shared__ bf16_t sA[128 * 64];
  __shared__ bf16_t sB[128 * 64];
  const int tid = threadIdx.x;
  const int w = tid >> 6;
  const int lane = tid & 63;
  const int l15 = lane & 15;
  const int quad = lane >> 4;
  const int wm = (w >> 1) * 64;
  const int wn = (w & 1) * 64;
  const int m0 = blockIdx.x * 128;
  const int n0 = blockIdx.y * 128;
  const int K = 1024;

  const int srow = lane >> 3;
  const int sgrp = (lane & 7) ^ srow;
  const bf16_t* aB = A + (size_t)(m0 + srow) * K + sgrp * 8;
  const bf16_t* bB = W + (size_t)(n0 + srow) * K + sgrp * 8;

  f32x4 acc[4][4];
#pragma unroll
  for (int i = 0; i < 4; ++i)
#pragma unroll
    for (int j = 0; j < 4; ++j) acc[i][j] = (f32x4){0.f, 0.f, 0.f, 0.f};

  for (int kt = 0; kt < K; kt += 64) {
#pragma unroll
    for (int i = 0; i < 4; ++i) {
      const int c = w * 4 + i;
      async_copy16(aB + (size_t)(c * 8) * K + kt, &sA[c * 512]);
      async_copy16(bB + (size_t)(c * 8) * K + kt, &sB[c * 512]);
    }
    __syncthreads();
#pragma unroll
    for (int ks = 0; ks < 2; ++ks) {
      bf16x8 af[4], bfv[4];
#pragma unroll
      for (int mi = 0; mi < 4; ++mi) {
        const int row = wm + mi * 16 + l15;
        const int grp = ks * 4 + quad;
        af[mi] = *(const bf16x8*)&sA[row * 64 + ((grp ^ (row & 7)) << 3)];
      }
#pragma unroll
      for (int ni = 0; ni < 4; ++ni) {
        const int row = wn + ni * 16 + l15;
        const int grp = ks * 4 + quad;
        bfv[ni] = *(const bf16x8*)&sB[row * 64 + ((grp ^ (row & 7)) << 3)];
      }
#pragma unroll
      for (int mi = 0; mi < 4; ++mi)
#pragma unroll
        for (int ni = 0; ni < 4; ++ni)
          acc[mi][ni] = __builtin_amdgcn_mfma_f32_16x16x32_bf16(
              af[mi], bfv[ni], acc[mi][ni], 0, 0, 0);
    }
    __syncthreads();
  }

  const int seg = n0 >> 10;  // 0=q 1=k 2=v (128-tile never straddles)
  const float scale = (seg == 0) ? qscale : 1.0f;
  const float* bp = (seg == 0) ? bq : ((seg == 1) ? bk : bv);
  float bvr[4];
#pragma unroll
  for (int ni = 0; ni < 4; ++ni)
    bvr[ni] = bp[(n0 + wn + ni * 16 + l15) & 1023];

  if (seg < 2) {
    bf16_t* out = (seg == 0) ? qb : kb;
#pragma unroll
    for (int mi = 0; mi < 4; ++mi) {
      const int rowb = m0 + wm + mi * 16 + quad * 4;
#pragma unroll
      for (int ni = 0; ni < 4; ++ni) {
        const int col = (n0 + wn + ni * 16 + l15) & 1023;
#pragma unroll
        for (int r = 0; r < 4; ++r)
          out[(size_t)(rowb + r) * 1024 + col] =
              (bf16_t)((acc[mi][ni][r] + bvr[ni]) * scale);
      }
    }
  } else {
#pragma unroll
    for (int mi = 0; mi < 4; ++mi) {
      const int rowb = m0 + wm + mi * 16 + quad * 4;
      const int bn = rowb >> 10;
      const int t = rowb & 1023;
#pragma unroll
      for (int ni = 0; ni < 4; ++ni) {
        const int u = (n0 + wn + ni * 16 + l15) & 1023;
        bf16x4 v4;
#pragma unroll
        for (int r = 0; r < 4; ++r) v4[r] = (bf16_t)(acc[mi][ni][r] + bvr[ni]);
        *(bf16x4*)&vtb[((size_t)(bn * 1024 + u)) * 1024 + t] = v4;
      }
    }
  }
}

// ---------------------------------------------------------------------------
// Out-proj GEMM (v5/m97 structure): C[8192,1024] = A @ W^T + b, fp32 out.
// launch_bounds(256,4): propagated from gemm_qkv's confirmed R10 win.
__global__ __launch_bounds__(256, 4) void gemm_out(
    const bf16_t* __restrict__ A, const bf16_t* __restrict__ W,
    const float* __restrict__ bias, float* __restrict__ Cout) {
  __shared__ bf16_t sA[128 * 64];
  __shared__ bf16_t sB[128 * 64];
  const int tid = threadIdx.x;
  const int w = tid >> 6;
  const int lane = tid & 63;
  const int l15 = lane & 15;
  const int quad = lane >> 4;
  const int wm = (w >> 1) * 64;
  const int wn = (w & 1) * 64;
  const int m0 = blockIdx.x * 128;
  const int n0 = blockIdx.y * 128;
  const int K = 1024, N = 1024;

  const int srow = lane >> 3;
  const int sgrp = (lane & 7) ^ srow;
  const bf16_t* aB = A + (size_t)(m0 + srow) * K + sgrp * 8;
  const bf16_t* bB = W + (size_t)(n0 + srow) * K + sgrp * 8;

  f32x4 acc[4][4];
#pragma unroll
  for (int i = 0; i < 4; ++i)
#pragma unroll
    for (int j = 0; j < 4; ++j) acc[i][j] = (f32x4){0.f, 0.f, 0.f, 0.f};

  for (int kt = 0; kt < K; kt += 64) {
#pragma unroll
    for (int i = 0; i < 4; ++i) {
      const int c = w * 4 + i;
      async_copy16(aB + (size_t)(c * 8) * K + kt, &sA[c * 512]);
      async_copy16(bB + (size_t)(c * 8) * K + kt, &sB[c * 512]);
    }
    __syncthreads();
#pragma unroll
    for (int ks = 0; ks < 2; ++ks) {
      bf16x8 af[4], bfv[4];
#pragma unroll
      for (int mi = 0; mi < 4; ++mi) {
        const int row = wm + mi * 16 + l15;
        const int grp = ks * 4 + quad;
        af[mi] = *(const bf16x8*)&sA[row * 64 + ((grp ^ (row & 7)) << 3)];
      }
#pragma unroll
      for (int ni = 0; ni < 4; ++ni) {
        const int row = wn + ni * 16 + l15;
        const int grp = ks * 4 + quad;
        bfv[ni] = *(const bf16x8*)&sB[row * 64 + ((grp ^ (row & 7)) << 3)];
      }
#pragma unroll
      for (int mi = 0; mi < 4; ++mi)
#pragma unroll
        for (int ni = 0; ni < 4; ++ni)
          acc[mi][ni] = __builtin_amdgcn_mfma_f32_16x16x32_bf16(
              af[mi], bfv[ni], acc[mi][ni], 0, 0, 0);
    }
    __syncthreads();
  }

  float bvr[4];
#pragma unroll
  for (int ni = 0; ni < 4; ++ni) bvr[ni] = bias[n0 + wn + ni * 16 + l15];
#pragma unroll
  for (int mi = 0; mi < 4; ++mi) {
    const int rowb = m0 + wm + mi * 16 + quad * 4;
#pragma unroll
    for (int ni = 0; ni < 4; ++ni) {
      const int col = n0 + wn + ni * 16 + l15;
#pragma unroll
      for (int r = 0; r < 4; ++r)
        Cout[(size_t)(rowb + r) * N + col] = acc[mi][ni][r] + bvr[ni];
    }
  }
}

// ---------------------------------------------------------------------------
// Flash attention v10: 2-phase pipelined, KVBLK=32, 32 steps. QK wave split
// changed to (q-half x s-half): wave w -> qm=(w&1)*32 (32 q), ws=(w>>1) (16
// s). Each kf LDS read now feeds 2 MFMAs (m loop) -> QK b128 reads 16->8
// per wave/step (attention is LDS-read-bound). PV + staging unchanged.
// grid = (32, 16): blockIdx.x = h + 8*b (XCD = h), blockIdx.y = qt (64 q).
__global__ __launch_bounds__(256, 2) void attention_k(
    const bf16_t* __restrict__ qb, const bf16_t* __restrict__ kb,
    const bf16_t* __restrict__ vtb, bf16_t* __restrict__ ob) {
  __shared__ bf16_t sK[2][32 * 256];  // [s][dk], 8-group XOR swizzle
  __shared__ bf16_t sV[2][256 * 32];  // [u][s], 4-group XOR swizzle
  __shared__ bf16_t sP[64 * 56];      // [q][s], pitch 56
  __shared__ float sL[2][64];         // per-ws-half row sums
  const int tid = threadIdx.x;
  const int w = tid >> 6;
  const int lane = tid & 63;
  const int l15 = lane & 15;
  const int quad = lane >> 4;
  const int h = blockIdx.x & 7, b = blockIdx.x >> 3, qt = blockIdx.y;
  const int t0 = qt * 64;
  const int qm = (w & 1) * 32;     // wave's q-row offset (QK and PV)
  const int ws = w >> 1;           // wave's s-half (16 s) in QK: 0,0,1,1
  const int uOff = (w >> 1) * 128; // wave's PV u-col offset
  const size_t qkrow0 =
      ((size_t)(b * 2 + (h >> 2)) * 1024) * 1024 + (h & 3) * 256;

  // Q fragments for this wave's 32 q-rows (K=32 MFMA B-layout)
  bf16x8 qf[2][8];
#pragma unroll
  for (int m = 0; m < 2; ++m) {
    const bf16_t* qrow =
        qb + qkrow0 + (size_t)(t0 + qm + m * 16 + l15) * 1024 + quad * 8;
#pragma unroll
    for (int kk = 0; kk < 8; ++kk)
      qf[m][kk] = *(const bf16x8*)(qrow + kk * 32);
  }

  f32x4 o[2][8];
#pragma unroll
  for (int m = 0; m < 2; ++m)
#pragma unroll
    for (int ct = 0; ct < 8; ++ct) o[m][ct] = (f32x4){0.f, 0.f, 0.f, 0.f};
  float lsum[2] = {0.f, 0.f};  // per-lane partial row sums (q=qm+m*16+l15)

  const int k_lr = lane >> 5;   // row parity within 2-row issue
  const int k_slot = lane & 31; // dk 8-group slot
  const int v_lr = lane >> 2;   // u row within 16-row issue
  const int v_slot = lane & 3;  // s 8-group slot

#define STAGE_KV(BUF, ST)                                                     \
  {                                                                           \
    _Pragma("unroll") for (int r = 0; r < 4; ++r) {                           \
      const int s = r * 8 + w * 2 + k_lr;                                     \
      const int g = k_slot ^ (s & 7);                                         \
      async_copy16(kb + qkrow0 + (size_t)((ST)*32 + s) * 1024 + g * 8,        \
                   &sK[BUF][(r * 8 + w * 2) * 256]);                          \
    }                                                                         \
    _Pragma("unroll") for (int r = 0; r < 4; ++r) {                           \
      const int c = r * 64 + w * 16 + v_lr;                                   \
      const int g = v_slot ^ ((c >> 1) & 3);                                  \
      async_copy16(                                                           \
          vtb +                                                               \
              ((size_t)(b * 2 + (c >> 7)) * 1024 + h * 128 + (c & 127)) *     \
                  1024 +                                                      \
              (ST)*32 + g * 8,                                                \
          &sV[BUF][(r * 64 + w * 16) * 32]);                                  \
    }                                                                         \
  }

  STAGE_KV(0, 0);
  bar_vm();

  for (int st = 0; st < 32; ++st) {
    const int cur = st & 1;
    if (st < 31) STAGE_KV(cur ^ 1, st + 1);

    // ---- S^T(16s x 32q) via mfma(kf, qf): col=l15=q, row=quad*4+r=s ----
    f32x4 s4[2];
#pragma unroll
    for (int m = 0; m < 2; ++m) s4[m] = (f32x4){0.f, 0.f, 0.f, 0.f};
    __builtin_amdgcn_s_setprio(1);
#pragma unroll
    for (int kk = 0; kk < 8; ++kk) {
      bf16x8 kf = *(const bf16x8*)&sK[cur][(ws * 16 + l15) * 256 +
                                          (((kk * 4 + quad) ^ (l15 & 7))
                                           << 3)];
#pragma unroll
      for (int m = 0; m < 2; ++m)
        s4[m] = __builtin_amdgcn_mfma_f32_16x16x32_bf16(kf, qf[m][kk], s4[m],
                                                        0, 0, 0);
    }
    __builtin_amdgcn_s_setprio(0);

    // ---- p = exp2(s): 4 s-consecutive values -> one b64 store ----
#pragma unroll
    for (int m = 0; m < 2; ++m) {
      bf16x4 p4;
      float ps = 0.f;
#pragma unroll
      for (int r = 0; r < 4; ++r) {
        const float p = __builtin_amdgcn_exp2f(s4[m][r]);
        p4[r] = (bf16_t)p;
        ps += p;
      }
      lsum[m] += ps;
      *(bf16x4*)&sP[(qm + m * 16 + l15) * 56 + ws * 16 + quad * 4] = p4;
    }
    bar_lds();  // P visible; staged global loads stay in flight

    // ---- O(32q x 128u) += P(32q x 32s) @ V'(32s x 128u) ----
    bf16x8 pf[2];
#pragma unroll
    for (int m = 0; m < 2; ++m)
      pf[m] = *(const bf16x8*)&sP[(qm + m * 16 + l15) * 56 + quad * 8];
    __builtin_amdgcn_s_setprio(1);
#pragma unroll
    for (int ct = 0; ct < 8; ++ct) {
      const int vrow = uOff + ct * 16 + l15;
      bf16x8 vf = *(const bf16x8*)&sV[cur][vrow * 32 +
                                           ((quad ^ ((vrow >> 1) & 3)) << 3)];
#pragma unroll
      for (int m = 0; m < 2; ++m)
        o[m][ct] = __builtin_amdgcn_mfma_f32_16x16x32_bf16(pf[m], vf, o[m][ct],
                                                           0, 0, 0);
    }
    __builtin_amdgcn_s_setprio(0);
    bar_vm();  // staged loads complete (covered by full step) + reads done
  }
#undef STAGE_KV

  // ---- final row-sum reduction: lane holds partials for q=qm+m*16+l15 ----
#pragma unroll
  for (int m = 0; m < 2; ++m) {
    float v = lsum[m];
    v += __shfl_xor(v, 16, 64);
    v += __shfl_xor(v, 32, 64);
    if (lane < 16) sL[ws][qm + m * 16 + l15] = v;
  }
  __syncthreads();

  // ---- epilogue: O * (1/l) -> ob[b, n, t, h*128+dv] ----
#pragma unroll
  for (int m = 0; m < 2; ++m) {
    float rl[4];
#pragma unroll
    for (int r = 0; r < 4; ++r) {
      const int row = qm + m * 16 + quad * 4 + r;
      rl[r] = 1.0f / (sL[0][row] + sL[1][row]);
    }
#pragma unroll
    for (int ct = 0; ct < 8; ++ct) {
      const int u = uOff + ct * 16 + l15;
      const int outc = h * 128 + (u & 127);
      const size_t rbase =
          ((size_t)(b * 2 + (u >> 7)) * 1024 + t0 + qm + m * 16 + quad * 4) *
              1024 +
          outc;
#pragma unroll
      for (int r = 0; r < 4; ++r)
        ob[rbase + (size_t)r * 1024] = (bf16_t)(o[m][ct][r] * rl[r]);
    }
  }
}

// ---------------------------------------------------------------------------
extern "C" void kernel_launch(void* const* d_in, const int* in_sizes, int n_in,
                              void* d_out, int out_size, void* d_ws,
                              size_t ws_size, hipStream_t stream) {
  const float* x = (const float*)d_in[0];
  const float* Wq = (const float*)d_in[2];
  const float* bq = (const float*)d_in[3];
  const float* Wk = (const float*)d_in[4];
  const float* bk = (const float*)d_in[5];
  const float* Wv = (const float*)d_in[6];
  const float* bv = (const float*)d_in[7];
  const float* Wo = (const float*)d_in[8];
  const float* bo = (const float*)d_in[9];
  float* out = (float*)d_out;

  char* ws = (char*)d_ws;
  const size_t MB = 1u << 20;
  bf16_t* xb = (bf16_t*)(ws);              // 16 MB; reused as ob after QKV
  bf16_t* qb = (bf16_t*)(ws + 16 * MB);    // 16 MB
  bf16_t* kb = (bf16_t*)(ws + 32 * MB);    // 16 MB
  bf16_t* vtb = (bf16_t*)(ws + 48 * MB);   // 16 MB
  bf16_t* wqkv = (bf16_t*)(ws + 64 * MB);  // 6 MB
  bf16_t* wob = (bf16_t*)(ws + 70 * MB);   // 2 MB
  bf16_t* ob = xb;  // x dead after QKV GEMM (stream-ordered)

  cast_all<<<6144, 256, 0, stream>>>(x, Wq, Wk, Wv, Wo, xb, wqkv, wob);

  // q scale = 1/sqrt(dk_co) * log2(e): softmax computed in exp2 domain
  gemm_qkv<<<dim3(64, 24), 256, 0, stream>>>(
      xb, wqkv, bq, bk, bv, qb, kb, vtb, 0.0625f * 1.4426950408889634f);

  // grid (h+8b, qt): XCD = linear%8 = h -> per-head K/V stays in one L2
  attention_k<<<dim3(32, 16), 256, 0, stream>>>(qb, kb, vtb, ob);

  gemm_out<<<dim3(64, 8), 256, 0, stream>>>(ob, wob, bo, out);
}

// Round 17
// 236.498 us; speedup vs baseline: 1.0079x; 1.0079x over previous
//
#include <hip/hip_runtime.h>
#include <cstdint>
#include <cstddef>

// ---------------------------------------------------------------------------
// MultiHeadCoAttention: B=4, NCH=2, T=1024, U=1024, H=8, D_K=128, dk_co=256.
// v11: R16 post-mortem: cross-run noise +-6% on unchanged kernels; attention
// invisible (<59us); gemm_qkv = only measurable target, at m97 plateau
// (920 TF, MfmaUtil 37). This round: gemm_qkv -> AITER-style counted-vmcnt
// pipeline: BK=32, 3-deep circular LDS (48KB, 3 blocks/CU), stage(t+2)
// during phase t, ONE barrier/phase with s_waitcnt vmcnt(4) lgkmcnt(0)
// (never vmcnt(0) in-loop). Swizzle for 32-elem rows: slot = quad ^
// ((r&3)^((r>>2)&3)), <=2-way banks both sides. gemm_out (m97 bound-4) and
// attention v10 unchanged (controls).
// ---------------------------------------------------------------------------

typedef __bf16 bf16_t;
typedef __attribute__((ext_vector_type(8))) __bf16 bf16x8;
typedef __attribute__((ext_vector_type(4))) __bf16 bf16x4;
typedef __attribute__((ext_vector_type(4))) float f32x4;

// async global->LDS, 16B per lane; LDS dest = wave-uniform base + lane*16
__device__ __forceinline__ void async_copy16(const bf16_t* g, bf16_t* l) {
  auto* gp = reinterpret_cast<const __attribute__((address_space(1))) void*>(
      reinterpret_cast<uintptr_t>(g));
  auto* lp = reinterpret_cast<__attribute__((address_space(3))) void*>(
      reinterpret_cast<uintptr_t>(l));
  __builtin_amdgcn_global_load_lds(gp, lp, 16, 0, 0);
}

// barrier with LDS-write visibility only (keeps staged global loads in flight)
__device__ __forceinline__ void bar_lds() {
  asm volatile("s_waitcnt lgkmcnt(0)" ::: "memory");
  __builtin_amdgcn_s_barrier();
  __builtin_amdgcn_sched_barrier(0);
}

// end-of-step barrier: drain staged loads + all LDS ops
__device__ __forceinline__ void bar_vm() {
  asm volatile("s_waitcnt vmcnt(0) lgkmcnt(0)" ::: "memory");
  __builtin_amdgcn_s_barrier();
  __builtin_amdgcn_sched_barrier(0);
}

// pipelined-GEMM phase barrier: retire the CURRENT tile's staged loads
// (4 newer loads = next tile's stage stay in flight) + close prev reads.
__device__ __forceinline__ void bar_pipe4() {
  asm volatile("s_waitcnt vmcnt(4) lgkmcnt(0)" ::: "memory");
  __builtin_amdgcn_s_barrier();
  __builtin_amdgcn_sched_barrier(0);
}

__device__ __forceinline__ void cast8(const float* s, bf16_t* d) {
  const float4 a = ((const float4*)s)[0];
  const float4 b = ((const float4*)s)[1];
  bf16x8 o;
  o[0] = (bf16_t)a.x; o[1] = (bf16_t)a.y; o[2] = (bf16_t)a.z; o[3] = (bf16_t)a.w;
  o[4] = (bf16_t)b.x; o[5] = (bf16_t)b.y; o[6] = (bf16_t)b.z; o[7] = (bf16_t)b.w;
  *(bf16x8*)d = o;
}

// ---------------------------------------------------------------------------
__global__ void cast_all(const float* __restrict__ x,
                         const float* __restrict__ Wq,
                         const float* __restrict__ Wk,
                         const float* __restrict__ Wv,
                         const float* __restrict__ Wo, bf16_t* __restrict__ xb,
                         bf16_t* __restrict__ wqkv, bf16_t* __restrict__ wob) {
  const int i = blockIdx.x * blockDim.x + threadIdx.x;
  if (i < 1048576) {
    cast8(x + (size_t)i * 8, xb + (size_t)i * 8);
  } else {
    const int j = i - 1048576;
    if (j < 393216) {
      const int seg = j >> 17;  // 131072 groups per weight
      const float* w = (seg == 0) ? Wq : ((seg == 1) ? Wk : Wv);
      cast8(w + (size_t)(j - seg * 131072) * 8, wqkv + (size_t)j * 8);
    } else if (j < 524288) {
      cast8(Wo + (size_t)(j - 393216) * 8, wob + (size_t)(j - 393216) * 8);
    }
  }
}

// ---------------------------------------------------------------------------
// Fused QKV GEMM v11: C[8192,3072] = xb @ Wqkv^T. Counted-vmcnt pipeline:
// BK=32, 3-deep circular buffers, stage(t+2) in phase t, vmcnt(4) per phase.
// Swizzle: LDS slot g holds global k-group g ^ MASK(row), MASK = (r&3)^((r>>2)&3).
__global__ __launch_bounds__(256, 3) void gemm_qkv(
    const bf16_t* __restrict__ A, const bf16_t* __restrict__ W,
    const float* __restrict__ bq, const float* __restrict__ bk,
    const float* __restrict__ bv, bf16_t* __restrict__ qb,
    bf16_t* __restrict__ kb, bf16_t* __restrict__ vtb, float qscale) {
  __shared__ bf16_t sA[3][128 * 32];
  __shared__ bf16_t sB[3][128 * 32];
  const int tid = threadIdx.x;
  const int w = tid >> 6;
  const int lane = tid & 63;
  const int l15 = lane & 15;
  const int quad = lane >> 4;
  const int wm = (w >> 1) * 64;
  const int wn = (w & 1) * 64;
  const int m0 = blockIdx.x * 128;
  const int n0 = blockIdx.y * 128;
  const int K = 1024;

#define MASK4(r) ((((r) & 3)) ^ (((r) >> 2) & 3))
  // staging constants: load j: linear i = tid + j*256; row=i>>2, slot=i&3
  const int i0 = tid, i1 = tid + 256;
  const int r0 = i0 >> 2, r1 = i1 >> 2;
  const int g0 = (i0 & 3) ^ MASK4(r0), g1 = (i1 & 3) ^ MASK4(r1);
  const bf16_t* aP0 = A + (size_t)(m0 + r0) * K + g0 * 8;
  const bf16_t* aP1 = A + (size_t)(m0 + r1) * K + g1 * 8;
  const bf16_t* bP0 = W + (size_t)(n0 + r0) * K + g0 * 8;
  const bf16_t* bP1 = W + (size_t)(n0 + r1) * K + g1 * 8;

#define STAGE(BUF, T)                                                         \
  {                                                                           \
    async_copy16(aP0 + (T)*32, &sA[BUF][i0 * 8]);                             \
    async_copy16(bP0 + (T)*32, &sB[BUF][i0 * 8]);                             \
    async_copy16(aP1 + (T)*32, &sA[BUF][i1 * 8]);                             \
    async_copy16(bP1 + (T)*32, &sB[BUF][i1 * 8]);                             \
  }

  f32x4 acc[4][4];
#pragma unroll
  for (int i = 0; i < 4; ++i)
#pragma unroll
    for (int j = 0; j < 4; ++j) acc[i][j] = (f32x4){0.f, 0.f, 0.f, 0.f};

  // fragment read offsets (within a 128x32 tile): row*32 + slot*8 elems
  int aOff[4], bOff[4];
#pragma unroll
  for (int mi = 0; mi < 4; ++mi) {
    const int row = wm + mi * 16 + l15;
    aOff[mi] = row * 32 + ((quad ^ MASK4(row)) << 3);
  }
#pragma unroll
  for (int ni = 0; ni < 4; ++ni) {
    const int row = wn + ni * 16 + l15;
    bOff[ni] = row * 32 + ((quad ^ MASK4(row)) << 3);
  }

  STAGE(0, 0);
  STAGE(1, 1);

  int cb = 0;  // buffer index = t % 3
  for (int t = 0; t < 32; ++t) {
    bar_pipe4();  // tile t landed (vmcnt(4): only stage(t+1) newer); prev reads closed
    if (t < 30) {
      const int sb = (cb == 0) ? 2 : cb - 1;  // (t+2) % 3
      STAGE(sb, t + 2);
    }
    bf16x8 af[4], bfv[4];
#pragma unroll
    for (int mi = 0; mi < 4; ++mi)
      af[mi] = *(const bf16x8*)&sA[cb][aOff[mi]];
#pragma unroll
    for (int ni = 0; ni < 4; ++ni)
      bfv[ni] = *(const bf16x8*)&sB[cb][bOff[ni]];
    __builtin_amdgcn_s_setprio(1);
#pragma unroll
    for (int mi = 0; mi < 4; ++mi)
#pragma unroll
      for (int ni = 0; ni < 4; ++ni)
        acc[mi][ni] = __builtin_amdgcn_mfma_f32_16x16x32_bf16(
            af[mi], bfv[ni], acc[mi][ni], 0, 0, 0);
    __builtin_amdgcn_s_setprio(0);
    cb = (cb == 2) ? 0 : cb + 1;
  }
#undef STAGE
#undef MASK4

  const int seg = n0 >> 10;  // 0=q 1=k 2=v (128-tile never straddles)
  const float scale = (seg == 0) ? qscale : 1.0f;
  const float* bp = (seg == 0) ? bq : ((seg == 1) ? bk : bv);
  float bvr[4];
#pragma unroll
  for (int ni = 0; ni < 4; ++ni)
    bvr[ni] = bp[(n0 + wn + ni * 16 + l15) & 1023];

  if (seg < 2) {
    bf16_t* out = (seg == 0) ? qb : kb;
#pragma unroll
    for (int mi = 0; mi < 4; ++mi) {
      const int rowb = m0 + wm + mi * 16 + quad * 4;
#pragma unroll
      for (int ni = 0; ni < 4; ++ni) {
        const int col = (n0 + wn + ni * 16 + l15) & 1023;
#pragma unroll
        for (int r = 0; r < 4; ++r)
          out[(size_t)(rowb + r) * 1024 + col] =
              (bf16_t)((acc[mi][ni][r] + bvr[ni]) * scale);
      }
    }
  } else {
#pragma unroll
    for (int mi = 0; mi < 4; ++mi) {
      const int rowb = m0 + wm + mi * 16 + quad * 4;
      const int bn = rowb >> 10;
      const int t = rowb & 1023;
#pragma unroll
      for (int ni = 0; ni < 4; ++ni) {
        const int u = (n0 + wn + ni * 16 + l15) & 1023;
        bf16x4 v4;
#pragma unroll
        for (int r = 0; r < 4; ++r) v4[r] = (bf16_t)(acc[mi][ni][r] + bvr[ni]);
        *(bf16x4*)&vtb[((size_t)(bn * 1024 + u)) * 1024 + t] = v4;
      }
    }
  }
}

// ---------------------------------------------------------------------------
// Out-proj GEMM (v5/m97 structure): C[8192,1024] = A @ W^T + b, fp32 out.
// launch_bounds(256,4). UNCHANGED (control).
__global__ __launch_bounds__(256, 4) void gemm_out(
    const bf16_t* __restrict__ A, const bf16_t* __restrict__ W,
    const float* __restrict__ bias, float* __restrict__ Cout) {
  __shared__ bf16_t sA[128 * 64];
  __shared__ bf16_t sB[128 * 64];
  const int tid = threadIdx.x;
  const int w = tid >> 6;
  const int lane = tid & 63;
  const int l15 = lane & 15;
  const int quad = lane >> 4;
  const int wm = (w >> 1) * 64;
  const int wn = (w & 1) * 64;
  const int m0 = blockIdx.x * 128;
  const int n0 = blockIdx.y * 128;
  const int K = 1024, N = 1024;

  const int srow = lane >> 3;
  const int sgrp = (lane & 7) ^ srow;
  const bf16_t* aB = A + (size_t)(m0 + srow) * K + sgrp * 8;
  const bf16_t* bB = W + (size_t)(n0 + srow) * K + sgrp * 8;

  f32x4 acc[4][4];
#pragma unroll
  for (int i = 0; i < 4; ++i)
#pragma unroll
    for (int j = 0; j < 4; ++j) acc[i][j] = (f32x4){0.f, 0.f, 0.f, 0.f};

  for (int kt = 0; kt < K; kt += 64) {
#pragma unroll
    for (int i = 0; i < 4; ++i) {
      const int c = w * 4 + i;
      async_copy16(aB + (size_t)(c * 8) * K + kt, &sA[c * 512]);
      async_copy16(bB + (size_t)(c * 8) * K + kt, &sB[c * 512]);
    }
    __syncthreads();
#pragma unroll
    for (int ks = 0; ks < 2; ++ks) {
      bf16x8 af[4], bfv[4];
#pragma unroll
      for (int mi = 0; mi < 4; ++mi) {
        const int row = wm + mi * 16 + l15;
        const int grp = ks * 4 + quad;
        af[mi] = *(const bf16x8*)&sA[row * 64 + ((grp ^ (row & 7)) << 3)];
      }
#pragma unroll
      for (int ni = 0; ni < 4; ++ni) {
        const int row = wn + ni * 16 + l15;
        const int grp = ks * 4 + quad;
        bfv[ni] = *(const bf16x8*)&sB[row * 64 + ((grp ^ (row & 7)) << 3)];
      }
#pragma unroll
      for (int mi = 0; mi < 4; ++mi)
#pragma unroll
        for (int ni = 0; ni < 4; ++ni)
          acc[mi][ni] = __builtin_amdgcn_mfma_f32_16x16x32_bf16(
              af[mi], bfv[ni], acc[mi][ni], 0, 0, 0);
    }
    __syncthreads();
  }

  float bvr[4];
#pragma unroll
  for (int ni = 0; ni < 4; ++ni) bvr[ni] = bias[n0 + wn + ni * 16 + l15];
#pragma unroll
  for (int mi = 0; mi < 4; ++mi) {
    const int rowb = m0 + wm + mi * 16 + quad * 4;
#pragma unroll
    for (int ni = 0; ni < 4; ++ni) {
      const int col = n0 + wn + ni * 16 + l15;
#pragma unroll
      for (int r = 0; r < 4; ++r)
        Cout[(size_t)(rowb + r) * N + col] = acc[mi][ni][r] + bvr[ni];
    }
  }
}

// ---------------------------------------------------------------------------
// Flash attention v10 (UNCHANGED, harness-verified R16): 2-phase pipelined,
// KVBLK=32, 32 steps; QK wave split 32q x 16s; grid (h+8b, qt).
__global__ __launch_bounds__(256, 2) void attention_k(
    const bf16_t* __restrict__ qb, const bf16_t* __restrict__ kb,
    const bf16_t* __restrict__ vtb, bf16_t* __restrict__ ob) {
  __shared__ bf16_t sK[2][32 * 256];  // [s][dk], 8-group XOR swizzle
  __shared__ bf16_t sV[2][256 * 32];  // [u][s], 4-group XOR swizzle
  __shared__ bf16_t sP[64 * 56];      // [q][s], pitch 56
  __shared__ float sL[2][64];         // per-ws-half row sums
  const int tid = threadIdx.x;
  const int w = tid >> 6;
  const int lane = tid & 63;
  const int l15 = lane & 15;
  const int quad = lane >> 4;
  const int h = blockIdx.x & 7, b = blockIdx.x >> 3, qt = blockIdx.y;
  const int t0 = qt * 64;
  const int qm = (w & 1) * 32;     // wave's q-row offset (QK and PV)
  const int ws = w >> 1;           // wave's s-half (16 s) in QK: 0,0,1,1
  const int uOff = (w >> 1) * 128; // wave's PV u-col offset
  const size_t qkrow0 =
      ((size_t)(b * 2 + (h >> 2)) * 1024) * 1024 + (h & 3) * 256;

  // Q fragments for this wave's 32 q-rows (K=32 MFMA B-layout)
  bf16x8 qf[2][8];
#pragma unroll
  for (int m = 0; m < 2; ++m) {
    const bf16_t* qrow =
        qb + qkrow0 + (size_t)(t0 + qm + m * 16 + l15) * 1024 + quad * 8;
#pragma unroll
    for (int kk = 0; kk < 8; ++kk)
      qf[m][kk] = *(const bf16x8*)(qrow + kk * 32);
  }

  f32x4 o[2][8];
#pragma unroll
  for (int m = 0; m < 2; ++m)
#pragma unroll
    for (int ct = 0; ct < 8; ++ct) o[m][ct] = (f32x4){0.f, 0.f, 0.f, 0.f};
  float lsum[2] = {0.f, 0.f};  // per-lane partial row sums (q=qm+m*16+l15)

  const int k_lr = lane >> 5;   // row parity within 2-row issue
  const int k_slot = lane & 31; // dk 8-group slot
  const int v_lr = lane >> 2;   // u row within 16-row issue
  const int v_slot = lane & 3;  // s 8-group slot

#define STAGE_KV(BUF, ST)                                                     \
  {                                                                           \
    _Pragma("unroll") for (int r = 0; r < 4; ++r) {                           \
      const int s = r * 8 + w * 2 + k_lr;                                     \
      const int g = k_slot ^ (s & 7);                                         \
      async_copy16(kb + qkrow0 + (size_t)((ST)*32 + s) * 1024 + g * 8,        \
                   &sK[BUF][(r * 8 + w * 2) * 256]);                          \
    }                                                                         \
    _Pragma("unroll") for (int r = 0; r < 4; ++r) {                           \
      const int c = r * 64 + w * 16 + v_lr;                                   \
      const int g = v_slot ^ ((c >> 1) & 3);                                  \
      async_copy16(                                                           \
          vtb +                                                               \
              ((size_t)(b * 2 + (c >> 7)) * 1024 + h * 128 + (c & 127)) *     \
                  1024 +                                                      \
              (ST)*32 + g * 8,                                                \
          &sV[BUF][(r * 64 + w * 16) * 32]);                                  \
    }                                                                         \
  }

  STAGE_KV(0, 0);
  bar_vm();

  for (int st = 0; st < 32; ++st) {
    const int cur = st & 1;
    if (st < 31) STAGE_KV(cur ^ 1, st + 1);

    // ---- S^T(16s x 32q) via mfma(kf, qf): col=l15=q, row=quad*4+r=s ----
    f32x4 s4[2];
#pragma unroll
    for (int m = 0; m < 2; ++m) s4[m] = (f32x4){0.f, 0.f, 0.f, 0.f};
    __builtin_amdgcn_s_setprio(1);
#pragma unroll
    for (int kk = 0; kk < 8; ++kk) {
      bf16x8 kf = *(const bf16x8*)&sK[cur][(ws * 16 + l15) * 256 +
                                          (((kk * 4 + quad) ^ (l15 & 7))
                                           << 3)];
#pragma unroll
      for (int m = 0; m < 2; ++m)
        s4[m] = __builtin_amdgcn_mfma_f32_16x16x32_bf16(kf, qf[m][kk], s4[m],
                                                        0, 0, 0);
    }
    __builtin_amdgcn_s_setprio(0);

    // ---- p = exp2(s): 4 s-consecutive values -> one b64 store ----
#pragma unroll
    for (int m = 0; m < 2; ++m) {
      bf16x4 p4;
      float ps = 0.f;
#pragma unroll
      for (int r = 0; r < 4; ++r) {
        const float p = __builtin_amdgcn_exp2f(s4[m][r]);
        p4[r] = (bf16_t)p;
        ps += p;
      }
      lsum[m] += ps;
      *(bf16x4*)&sP[(qm + m * 16 + l15) * 56 + ws * 16 + quad * 4] = p4;
    }
    bar_lds();  // P visible; staged global loads stay in flight

    // ---- O(32q x 128u) += P(32q x 32s) @ V'(32s x 128u) ----
    bf16x8 pf[2];
#pragma unroll
    for (int m = 0; m < 2; ++m)
      pf[m] = *(const bf16x8*)&sP[(qm + m * 16 + l15) * 56 + quad * 8];
    __builtin_amdgcn_s_setprio(1);
#pragma unroll
    for (int ct = 0; ct < 8; ++ct) {
      const int vrow = uOff + ct * 16 + l15;
      bf16x8 vf = *(const bf16x8*)&sV[cur][vrow * 32 +
                                           ((quad ^ ((vrow >> 1) & 3)) << 3)];
#pragma unroll
      for (int m = 0; m < 2; ++m)
        o[m][ct] = __builtin_amdgcn_mfma_f32_16x16x32_bf16(pf[m], vf, o[m][ct],
                                                           0, 0, 0);
    }
    __builtin_amdgcn_s_setprio(0);
    bar_vm();  // staged loads complete (covered by full step) + reads done
  }
#undef STAGE_KV

  // ---- final row-sum reduction: lane holds partials for q=qm+m*16+l15 ----
#pragma unroll
  for (int m = 0; m < 2; ++m) {
    float v = lsum[m];
    v += __shfl_xor(v, 16, 64);
    v += __shfl_xor(v, 32, 64);
    if (lane < 16) sL[ws][qm + m * 16 + l15] = v;
  }
  __syncthreads();

  // ---- epilogue: O * (1/l) -> ob[b, n, t, h*128+dv] ----
#pragma unroll
  for (int m = 0; m < 2; ++m) {
    float rl[4];
#pragma unroll
    for (int r = 0; r < 4; ++r) {
      const int row = qm + m * 16 + quad * 4 + r;
      rl[r] = 1.0f / (sL[0][row] + sL[1][row]);
    }
#pragma unroll
    for (int ct = 0; ct < 8; ++ct) {
      const int u = uOff + ct * 16 + l15;
      const int outc = h * 128 + (u & 127);
      const size_t rbase =
          ((size_t)(b * 2 + (u >> 7)) * 1024 + t0 + qm + m * 16 + quad * 4) *
              1024 +
          outc;
#pragma unroll
      for (int r = 0; r < 4; ++r)
        ob[rbase + (size_t)r * 1024] = (bf16_t)(o[m][ct][r] * rl[r]);
    }
  }
}

// ---------------------------------------------------------------------------
extern "C" void kernel_launch(void* const* d_in, const int* in_sizes, int n_in,
                              void* d_out, int out_size, void* d_ws,
                              size_t ws_size, hipStream_t stream) {
  const float* x = (const float*)d_in[0];
  const float* Wq = (const float*)d_in[2];
  const float* bq = (const float*)d_in[3];
  const float* Wk = (const float*)d_in[4];
  const float* bk = (const float*)d_in[5];
  const float* Wv = (const float*)d_in[6];
  const float* bv = (const float*)d_in[7];
  const float* Wo = (const float*)d_in[8];
  const float* bo = (const float*)d_in[9];
  float* out = (float*)d_out;

  char* ws = (char*)d_ws;
  const size_t MB = 1u << 20;
  bf16_t* xb = (bf16_t*)(ws);              // 16 MB; reused as ob after QKV
  bf16_t* qb = (bf16_t*)(ws + 16 * MB);    // 16 MB
  bf16_t* kb = (bf16_t*)(ws + 32 * MB);    // 16 MB
  bf16_t* vtb = (bf16_t*)(ws + 48 * MB);   // 16 MB
  bf16_t* wqkv = (bf16_t*)(ws + 64 * MB);  // 6 MB
  bf16_t* wob = (bf16_t*)(ws + 70 * MB);   // 2 MB
  bf16_t* ob = xb;  // x dead after QKV GEMM (stream-ordered)

  cast_all<<<6144, 256, 0, stream>>>(x, Wq, Wk, Wv, Wo, xb, wqkv, wob);

  // q scale = 1/sqrt(dk_co) * log2(e): softmax computed in exp2 domain
  gemm_qkv<<<dim3(64, 24), 256, 0, stream>>>(
      xb, wqkv, bq, bk, bv, qb, kb, vtb, 0.0625f * 1.4426950408889634f);

  // grid (h+8b, qt): XCD = linear%8 = h -> per-head K/V stays in one L2
  attention_k<<<dim3(32, 16), 256, 0, stream>>>(qb, kb, vtb, ob);

  gemm_out<<<dim3(64, 8), 256, 0, stream>>>(ob, wob, bo, out);
}

// Round 18
// 231.044 us; speedup vs baseline: 1.0317x; 1.0236x over previous
//
#include <hip/hip_runtime.h>
#include <cstdint>
#include <cstddef>

// ---------------------------------------------------------------------------
// MultiHeadCoAttention: B=4, NCH=2, T=1024, U=1024, H=8, D_K=128, dk_co=256.
// v12: R17 post-mortem: v11 counted-vmcnt pipeline REGRESSED (59.5->71.5us,
// SQ_LDS_BANK_CONFLICT 0->6.29M = the entire regression): in-flight
// global_load_lds writes collide with same-step ds_reads at the LDS banks.
// m97 plateau confirmed structural at 128^2. This round: gemm_qkv reverted
// to verified v5/bound-4 + XCD-chunk block swizzle (each XCD: 8 m-tiles x
// all n-tiles -> 2MB A-panel set L2-resident; FETCH 42 -> pred 24-32 MB).
// gemm_out (v5 bound-4) and attention v10 unchanged (R16-verified).
// ---------------------------------------------------------------------------

typedef __bf16 bf16_t;
typedef __attribute__((ext_vector_type(8))) __bf16 bf16x8;
typedef __attribute__((ext_vector_type(4))) __bf16 bf16x4;
typedef __attribute__((ext_vector_type(4))) float f32x4;

// async global->LDS, 16B per lane; LDS dest = wave-uniform base + lane*16
__device__ __forceinline__ void async_copy16(const bf16_t* g, bf16_t* l) {
  auto* gp = reinterpret_cast<const __attribute__((address_space(1))) void*>(
      reinterpret_cast<uintptr_t>(g));
  auto* lp = reinterpret_cast<__attribute__((address_space(3))) void*>(
      reinterpret_cast<uintptr_t>(l));
  __builtin_amdgcn_global_load_lds(gp, lp, 16, 0, 0);
}

// barrier with LDS-write visibility only (keeps staged global loads in flight)
__device__ __forceinline__ void bar_lds() {
  asm volatile("s_waitcnt lgkmcnt(0)" ::: "memory");
  __builtin_amdgcn_s_barrier();
  __builtin_amdgcn_sched_barrier(0);
}

// end-of-step barrier: drain staged loads + all LDS ops
__device__ __forceinline__ void bar_vm() {
  asm volatile("s_waitcnt vmcnt(0) lgkmcnt(0)" ::: "memory");
  __builtin_amdgcn_s_barrier();
  __builtin_amdgcn_sched_barrier(0);
}

__device__ __forceinline__ void cast8(const float* s, bf16_t* d) {
  const float4 a = ((const float4*)s)[0];
  const float4 b = ((const float4*)s)[1];
  bf16x8 o;
  o[0] = (bf16_t)a.x; o[1] = (bf16_t)a.y; o[2] = (bf16_t)a.z; o[3] = (bf16_t)a.w;
  o[4] = (bf16_t)b.x; o[5] = (bf16_t)b.y; o[6] = (bf16_t)b.z; o[7] = (bf16_t)b.w;
  *(bf16x8*)d = o;
}

// ---------------------------------------------------------------------------
__global__ void cast_all(const float* __restrict__ x,
                         const float* __restrict__ Wq,
                         const float* __restrict__ Wk,
                         const float* __restrict__ Wv,
                         const float* __restrict__ Wo, bf16_t* __restrict__ xb,
                         bf16_t* __restrict__ wqkv, bf16_t* __restrict__ wob) {
  const int i = blockIdx.x * blockDim.x + threadIdx.x;
  if (i < 1048576) {
    cast8(x + (size_t)i * 8, xb + (size_t)i * 8);
  } else {
    const int j = i - 1048576;
    if (j < 393216) {
      const int seg = j >> 17;  // 131072 groups per weight
      const float* w = (seg == 0) ? Wq : ((seg == 1) ? Wk : Wv);
      cast8(w + (size_t)(j - seg * 131072) * 8, wqkv + (size_t)j * 8);
    } else if (j < 524288) {
      cast8(Wo + (size_t)(j - 393216) * 8, wob + (size_t)(j - 393216) * 8);
    }
  }
}

// ---------------------------------------------------------------------------
// Fused QKV GEMM (v5/m97 structure, bound-4: verified R10/R16 56-59.5us):
// C[8192,3072] = xb @ Wqkv^T. NEW: XCD-chunk swizzle -- lin%8 = XCD; each
// XCD owns m-tiles [8x,8x+8) x all 24 n-tiles (bijective remap), so its 2MB
// A-panel set stays L2-resident for the whole dispatch.
__global__ __launch_bounds__(256, 4) void gemm_qkv(
    const bf16_t* __restrict__ A, const bf16_t* __restrict__ W,
    const float* __restrict__ bq, const float* __restrict__ bk,
    const float* __restrict__ bv, bf16_t* __restrict__ qb,
    bf16_t* __restrict__ kb, bf16_t* __restrict__ vtb, float qscale) {
  __shared__ bf16_t sA[128 * 64];
  __shared__ bf16_t sB[128 * 64];
  const int tid = threadIdx.x;
  const int w = tid >> 6;
  const int lane = tid & 63;
  const int l15 = lane & 15;
  const int quad = lane >> 4;
  const int wm = (w >> 1) * 64;
  const int wn = (w & 1) * 64;
  // XCD-chunk swizzle: lin in [0,1536); xcd = lin&7 (HW: XCD = lin%8).
  // mt = xcd*8 + (idx&7) in [0,64), nt = idx>>3 in [0,24). Bijective.
  const int lin = blockIdx.y * 64 + blockIdx.x;
  const int xcd = lin & 7, idx = lin >> 3;
  const int m0 = (xcd * 8 + (idx & 7)) * 128;
  const int n0 = (idx >> 3) * 128;
  const int K = 1024;

  const int srow = lane >> 3;
  const int sgrp = (lane & 7) ^ srow;
  const bf16_t* aB = A + (size_t)(m0 + srow) * K + sgrp * 8;
  const bf16_t* bB = W + (size_t)(n0 + srow) * K + sgrp * 8;

  f32x4 acc[4][4];
#pragma unroll
  for (int i = 0; i < 4; ++i)
#pragma unroll
    for (int j = 0; j < 4; ++j) acc[i][j] = (f32x4){0.f, 0.f, 0.f, 0.f};

  for (int kt = 0; kt < K; kt += 64) {
#pragma unroll
    for (int i = 0; i < 4; ++i) {
      const int c = w * 4 + i;
      async_copy16(aB + (size_t)(c * 8) * K + kt, &sA[c * 512]);
      async_copy16(bB + (size_t)(c * 8) * K + kt, &sB[c * 512]);
    }
    __syncthreads();
#pragma unroll
    for (int ks = 0; ks < 2; ++ks) {
      bf16x8 af[4], bfv[4];
#pragma unroll
      for (int mi = 0; mi < 4; ++mi) {
        const int row = wm + mi * 16 + l15;
        const int grp = ks * 4 + quad;
        af[mi] = *(const bf16x8*)&sA[row * 64 + ((grp ^ (row & 7)) << 3)];
      }
#pragma unroll
      for (int ni = 0; ni < 4; ++ni) {
        const int row = wn + ni * 16 + l15;
        const int grp = ks * 4 + quad;
        bfv[ni] = *(const bf16x8*)&sB[row * 64 + ((grp ^ (row & 7)) << 3)];
      }
#pragma unroll
      for (int mi = 0; mi < 4; ++mi)
#pragma unroll
        for (int ni = 0; ni < 4; ++ni)
          acc[mi][ni] = __builtin_amdgcn_mfma_f32_16x16x32_bf16(
              af[mi], bfv[ni], acc[mi][ni], 0, 0, 0);
    }
    __syncthreads();
  }

  const int seg = n0 >> 10;  // 0=q 1=k 2=v (128-tile never straddles)
  const float scale = (seg == 0) ? qscale : 1.0f;
  const float* bp = (seg == 0) ? bq : ((seg == 1) ? bk : bv);
  float bvr[4];
#pragma unroll
  for (int ni = 0; ni < 4; ++ni)
    bvr[ni] = bp[(n0 + wn + ni * 16 + l15) & 1023];

  if (seg < 2) {
    bf16_t* out = (seg == 0) ? qb : kb;
#pragma unroll
    for (int mi = 0; mi < 4; ++mi) {
      const int rowb = m0 + wm + mi * 16 + quad * 4;
#pragma unroll
      for (int ni = 0; ni < 4; ++ni) {
        const int col = (n0 + wn + ni * 16 + l15) & 1023;
#pragma unroll
        for (int r = 0; r < 4; ++r)
          out[(size_t)(rowb + r) * 1024 + col] =
              (bf16_t)((acc[mi][ni][r] + bvr[ni]) * scale);
      }
    }
  } else {
#pragma unroll
    for (int mi = 0; mi < 4; ++mi) {
      const int rowb = m0 + wm + mi * 16 + quad * 4;
      const int bn = rowb >> 10;
      const int t = rowb & 1023;
#pragma unroll
      for (int ni = 0; ni < 4; ++ni) {
        const int u = (n0 + wn + ni * 16 + l15) & 1023;
        bf16x4 v4;
#pragma unroll
        for (int r = 0; r < 4; ++r) v4[r] = (bf16_t)(acc[mi][ni][r] + bvr[ni]);
        *(bf16x4*)&vtb[((size_t)(bn * 1024 + u)) * 1024 + t] = v4;
      }
    }
  }
}

// ---------------------------------------------------------------------------
// Out-proj GEMM (v5/m97 structure): C[8192,1024] = A @ W^T + b, fp32 out.
// launch_bounds(256,4). UNCHANGED (control).
__global__ __launch_bounds__(256, 4) void gemm_out(
    const bf16_t* __restrict__ A, const bf16_t* __restrict__ W,
    const float* __restrict__ bias, float* __restrict__ Cout) {
  __shared__ bf16_t sA[128 * 64];
  __shared__ bf16_t sB[128 * 64];
  const int tid = threadIdx.x;
  const int w = tid >> 6;
  const int lane = tid & 63;
  const int l15 = lane & 15;
  const int quad = lane >> 4;
  const int wm = (w >> 1) * 64;
  const int wn = (w & 1) * 64;
  const int m0 = blockIdx.x * 128;
  const int n0 = blockIdx.y * 128;
  const int K = 1024, N = 1024;

  const int srow = lane >> 3;
  const int sgrp = (lane & 7) ^ srow;
  const bf16_t* aB = A + (size_t)(m0 + srow) * K + sgrp * 8;
  const bf16_t* bB = W + (size_t)(n0 + srow) * K + sgrp * 8;

  f32x4 acc[4][4];
#pragma unroll
  for (int i = 0; i < 4; ++i)
#pragma unroll
    for (int j = 0; j < 4; ++j) acc[i][j] = (f32x4){0.f, 0.f, 0.f, 0.f};

  for (int kt = 0; kt < K; kt += 64) {
#pragma unroll
    for (int i = 0; i < 4; ++i) {
      const int c = w * 4 + i;
      async_copy16(aB + (size_t)(c * 8) * K + kt, &sA[c * 512]);
      async_copy16(bB + (size_t)(c * 8) * K + kt, &sB[c * 512]);
    }
    __syncthreads();
#pragma unroll
    for (int ks = 0; ks < 2; ++ks) {
      bf16x8 af[4], bfv[4];
#pragma unroll
      for (int mi = 0; mi < 4; ++mi) {
        const int row = wm + mi * 16 + l15;
        const int grp = ks * 4 + quad;
        af[mi] = *(const bf16x8*)&sA[row * 64 + ((grp ^ (row & 7)) << 3)];
      }
#pragma unroll
      for (int ni = 0; ni < 4; ++ni) {
        const int row = wn + ni * 16 + l15;
        const int grp = ks * 4 + quad;
        bfv[ni] = *(const bf16x8*)&sB[row * 64 + ((grp ^ (row & 7)) << 3)];
      }
#pragma unroll
      for (int mi = 0; mi < 4; ++mi)
#pragma unroll
        for (int ni = 0; ni < 4; ++ni)
          acc[mi][ni] = __builtin_amdgcn_mfma_f32_16x16x32_bf16(
              af[mi], bfv[ni], acc[mi][ni], 0, 0, 0);
    }
    __syncthreads();
  }

  float bvr[4];
#pragma unroll
  for (int ni = 0; ni < 4; ++ni) bvr[ni] = bias[n0 + wn + ni * 16 + l15];
#pragma unroll
  for (int mi = 0; mi < 4; ++mi) {
    const int rowb = m0 + wm + mi * 16 + quad * 4;
#pragma unroll
    for (int ni = 0; ni < 4; ++ni) {
      const int col = n0 + wn + ni * 16 + l15;
#pragma unroll
      for (int r = 0; r < 4; ++r)
        Cout[(size_t)(rowb + r) * N + col] = acc[mi][ni][r] + bvr[ni];
    }
  }
}

// ---------------------------------------------------------------------------
// Flash attention v10 (UNCHANGED, harness-verified R16): 2-phase pipelined,
// KVBLK=32, 32 steps; QK wave split 32q x 16s; grid (h+8b, qt).
__global__ __launch_bounds__(256, 2) void attention_k(
    const bf16_t* __restrict__ qb, const bf16_t* __restrict__ kb,
    const bf16_t* __restrict__ vtb, bf16_t* __restrict__ ob) {
  __shared__ bf16_t sK[2][32 * 256];  // [s][dk], 8-group XOR swizzle
  __shared__ bf16_t sV[2][256 * 32];  // [u][s], 4-group XOR swizzle
  __shared__ bf16_t sP[64 * 56];      // [q][s], pitch 56
  __shared__ float sL[2][64];         // per-ws-half row sums
  const int tid = threadIdx.x;
  const int w = tid >> 6;
  const int lane = tid & 63;
  const int l15 = lane & 15;
  const int quad = lane >> 4;
  const int h = blockIdx.x & 7, b = blockIdx.x >> 3, qt = blockIdx.y;
  const int t0 = qt * 64;
  const int qm = (w & 1) * 32;     // wave's q-row offset (QK and PV)
  const int ws = w >> 1;           // wave's s-half (16 s) in QK: 0,0,1,1
  const int uOff = (w >> 1) * 128; // wave's PV u-col offset
  const size_t qkrow0 =
      ((size_t)(b * 2 + (h >> 2)) * 1024) * 1024 + (h & 3) * 256;

  // Q fragments for this wave's 32 q-rows (K=32 MFMA B-layout)
  bf16x8 qf[2][8];
#pragma unroll
  for (int m = 0; m < 2; ++m) {
    const bf16_t* qrow =
        qb + qkrow0 + (size_t)(t0 + qm + m * 16 + l15) * 1024 + quad * 8;
#pragma unroll
    for (int kk = 0; kk < 8; ++kk)
      qf[m][kk] = *(const bf16x8*)(qrow + kk * 32);
  }

  f32x4 o[2][8];
#pragma unroll
  for (int m = 0; m < 2; ++m)
#pragma unroll
    for (int ct = 0; ct < 8; ++ct) o[m][ct] = (f32x4){0.f, 0.f, 0.f, 0.f};
  float lsum[2] = {0.f, 0.f};  // per-lane partial row sums (q=qm+m*16+l15)

  const int k_lr = lane >> 5;   // row parity within 2-row issue
  const int k_slot = lane & 31; // dk 8-group slot
  const int v_lr = lane >> 2;   // u row within 16-row issue
  const int v_slot = lane & 3;  // s 8-group slot

#define STAGE_KV(BUF, ST)                                                     \
  {                                                                           \
    _Pragma("unroll") for (int r = 0; r < 4; ++r) {                           \
      const int s = r * 8 + w * 2 + k_lr;                                     \
      const int g = k_slot ^ (s & 7);                                         \
      async_copy16(kb + qkrow0 + (size_t)((ST)*32 + s) * 1024 + g * 8,        \
                   &sK[BUF][(r * 8 + w * 2) * 256]);                          \
    }                                                                         \
    _Pragma("unroll") for (int r = 0; r < 4; ++r) {                           \
      const int c = r * 64 + w * 16 + v_lr;                                   \
      const int g = v_slot ^ ((c >> 1) & 3);                                  \
      async_copy16(                                                           \
          vtb +                                                               \
              ((size_t)(b * 2 + (c >> 7)) * 1024 + h * 128 + (c & 127)) *     \
                  1024 +                                                      \
              (ST)*32 + g * 8,                                                \
          &sV[BUF][(r * 64 + w * 16) * 32]);                                  \
    }                                                                         \
  }

  STAGE_KV(0, 0);
  bar_vm();

  for (int st = 0; st < 32; ++st) {
    const int cur = st & 1;
    if (st < 31) STAGE_KV(cur ^ 1, st + 1);

    // ---- S^T(16s x 32q) via mfma(kf, qf): col=l15=q, row=quad*4+r=s ----
    f32x4 s4[2];
#pragma unroll
    for (int m = 0; m < 2; ++m) s4[m] = (f32x4){0.f, 0.f, 0.f, 0.f};
    __builtin_amdgcn_s_setprio(1);
#pragma unroll
    for (int kk = 0; kk < 8; ++kk) {
      bf16x8 kf = *(const bf16x8*)&sK[cur][(ws * 16 + l15) * 256 +
                                          (((kk * 4 + quad) ^ (l15 & 7))
                                           << 3)];
#pragma unroll
      for (int m = 0; m < 2; ++m)
        s4[m] = __builtin_amdgcn_mfma_f32_16x16x32_bf16(kf, qf[m][kk], s4[m],
                                                        0, 0, 0);
    }
    __builtin_amdgcn_s_setprio(0);

    // ---- p = exp2(s): 4 s-consecutive values -> one b64 store ----
#pragma unroll
    for (int m = 0; m < 2; ++m) {
      bf16x4 p4;
      float ps = 0.f;
#pragma unroll
      for (int r = 0; r < 4; ++r) {
        const float p = __builtin_amdgcn_exp2f(s4[m][r]);
        p4[r] = (bf16_t)p;
        ps += p;
      }
      lsum[m] += ps;
      *(bf16x4*)&sP[(qm + m * 16 + l15) * 56 + ws * 16 + quad * 4] = p4;
    }
    bar_lds();  // P visible; staged global loads stay in flight

    // ---- O(32q x 128u) += P(32q x 32s) @ V'(32s x 128u) ----
    bf16x8 pf[2];
#pragma unroll
    for (int m = 0; m < 2; ++m)
      pf[m] = *(const bf16x8*)&sP[(qm + m * 16 + l15) * 56 + quad * 8];
    __builtin_amdgcn_s_setprio(1);
#pragma unroll
    for (int ct = 0; ct < 8; ++ct) {
      const int vrow = uOff + ct * 16 + l15;
      bf16x8 vf = *(const bf16x8*)&sV[cur][vrow * 32 +
                                           ((quad ^ ((vrow >> 1) & 3)) << 3)];
#pragma unroll
      for (int m = 0; m < 2; ++m)
        o[m][ct] = __builtin_amdgcn_mfma_f32_16x16x32_bf16(pf[m], vf, o[m][ct],
                                                           0, 0, 0);
    }
    __builtin_amdgcn_s_setprio(0);
    bar_vm();  // staged loads complete (covered by full step) + reads done
  }
#undef STAGE_KV

  // ---- final row-sum reduction: lane holds partials for q=qm+m*16+l15 ----
#pragma unroll
  for (int m = 0; m < 2; ++m) {
    float v = lsum[m];
    v += __shfl_xor(v, 16, 64);
    v += __shfl_xor(v, 32, 64);
    if (lane < 16) sL[ws][qm + m * 16 + l15] = v;
  }
  __syncthreads();

  // ---- epilogue: O * (1/l) -> ob[b, n, t, h*128+dv] ----
#pragma unroll
  for (int m = 0; m < 2; ++m) {
    float rl[4];
#pragma unroll
    for (int r = 0; r < 4; ++r) {
      const int row = qm + m * 16 + quad * 4 + r;
      rl[r] = 1.0f / (sL[0][row] + sL[1][row]);
    }
#pragma unroll
    for (int ct = 0; ct < 8; ++ct) {
      const int u = uOff + ct * 16 + l15;
      const int outc = h * 128 + (u & 127);
      const size_t rbase =
          ((size_t)(b * 2 + (u >> 7)) * 1024 + t0 + qm + m * 16 + quad * 4) *
              1024 +
          outc;
#pragma unroll
      for (int r = 0; r < 4; ++r)
        ob[rbase + (size_t)r * 1024] = (bf16_t)(o[m][ct][r] * rl[r]);
    }
  }
}

// ---------------------------------------------------------------------------
extern "C" void kernel_launch(void* const* d_in, const int* in_sizes, int n_in,
                              void* d_out, int out_size, void* d_ws,
                              size_t ws_size, hipStream_t stream) {
  const float* x = (const float*)d_in[0];
  const float* Wq = (const float*)d_in[2];
  const float* bq = (const float*)d_in[3];
  const float* Wk = (const float*)d_in[4];
  const float* bk = (const float*)d_in[5];
  const float* Wv = (const float*)d_in[6];
  const float* bv = (const float*)d_in[7];
  const float* Wo = (const float*)d_in[8];
  const float* bo = (const float*)d_in[9];
  float* out = (float*)d_out;

  char* ws = (char*)d_ws;
  const size_t MB = 1u << 20;
  bf16_t* xb = (bf16_t*)(ws);              // 16 MB; reused as ob after QKV
  bf16_t* qb = (bf16_t*)(ws + 16 * MB);    // 16 MB
  bf16_t* kb = (bf16_t*)(ws + 32 * MB);    // 16 MB
  bf16_t* vtb = (bf16_t*)(ws + 48 * MB);   // 16 MB
  bf16_t* wqkv = (bf16_t*)(ws + 64 * MB);  // 6 MB
  bf16_t* wob = (bf16_t*)(ws + 70 * MB);   // 2 MB
  bf16_t* ob = xb;  // x dead after QKV GEMM (stream-ordered)

  cast_all<<<6144, 256, 0, stream>>>(x, Wq, Wk, Wv, Wo, xb, wqkv, wob);

  // q scale = 1/sqrt(dk_co) * log2(e): softmax computed in exp2 domain
  gemm_qkv<<<dim3(64, 24), 256, 0, stream>>>(
      xb, wqkv, bq, bk, bv, qb, kb, vtb, 0.0625f * 1.4426950408889634f);

  // grid (h+8b, qt): XCD = linear%8 = h -> per-head K/V stays in one L2
  attention_k<<<dim3(32, 16), 256, 0, stream>>>(qb, kb, vtb, ob);

  gemm_out<<<dim3(64, 8), 256, 0, stream>>>(ob, wob, bo, out);
}